// Round 1
// baseline (124.356 us; speedup 1.0000x reference)
//
#include <hip/hip_runtime.h>
#include <math.h>

#define NBLK_B 8  // phase-B persistent blocks (cols of W1 partitioned 8 x 128)

__device__ __forceinline__ float rho(float s) {
  return fminf(fmaxf(s, 0.0f), 1.0f);
}

// d/ds clip(s,0,1) with JAX maximum/minimum tie-gradient = 0.5
__device__ __forceinline__ float drho(float s) {
  if (s < 0.0f || s > 1.0f) return 0.0f;
  float g = 1.0f;
  if (s == 0.0f) g *= 0.5f;
  if (s == 1.0f) g *= 0.5f;
  return g;
}

// ---------------- Phase A: per-block partials of c0 = rho(x) @ W0 ----------
// W0 row-major [N,128]; each block handles 512 rows; partials -> ws (det.)
__global__ __launch_bounds__(256) void k1_xw0(const float* __restrict__ x,
                                              const float* __restrict__ W0,
                                              float* __restrict__ part,
                                              int* __restrict__ cnt) {
  __shared__ float xs[512];
  __shared__ float red[8][132];  // +4 pad to spread store banks
  const int t = threadIdx.x;
  const int b = blockIdx.x;
  if (b == 0 && t == 0) cnt[0] = 0;  // reset phase-B barrier (stream-ordered)
  const int r0 = b << 9;
  for (int i = t; i < 512; i += 256) xs[i] = rho(x[r0 + i]);
  __syncthreads();
  const int cq = t & 31;   // float4 column group (32 x 4 = 128 cols)
  const int rg = t >> 5;   // row group 0..7, 64 rows each
  const float4* __restrict__ W4 = reinterpret_cast<const float4*>(W0);
  float ax = 0.f, ay = 0.f, az = 0.f, aw = 0.f;
  const int base = (r0 + rg * 64) * 32 + cq;
#pragma unroll 8
  for (int i = 0; i < 64; ++i) {
    const float xv = xs[rg * 64 + i];
    const float4 w = W4[base + i * 32];
    ax = fmaf(xv, w.x, ax);
    ay = fmaf(xv, w.y, ay);
    az = fmaf(xv, w.z, az);
    aw = fmaf(xv, w.w, aw);
  }
  red[rg][cq * 4 + 0] = ax;
  red[rg][cq * 4 + 1] = ay;
  red[rg][cq * 4 + 2] = az;
  red[rg][cq * 4 + 3] = aw;
  __syncthreads();
  if (t < 128) {
    float s = 0.f;
#pragma unroll
    for (int g = 0; g < 8; ++g) s += red[g][t];
    part[b * 128 + t] = s;
  }
}

// ---------------- Phase B: persistent 8-block Adam iterator -----------------
// Block p owns W1 columns [128p,128p+128) in XOR-swizzled LDS, o-segment
// [128p,128p+128) in registers; h (128) replicated bit-identically per block.
// Per iteration, only partial_a (8 x 128 f32) crosses blocks via one
// device-scope spin barrier.
__global__ __launch_bounds__(256) void k2_iter(const float* __restrict__ part,
                                               const int npart,
                                               const float* __restrict__ W1,
                                               const float* __restrict__ b1,
                                               const float* __restrict__ b2,
                                               const int* __restrict__ niterp,
                                               float* __restrict__ aPartG,
                                               int* __restrict__ cnt,
                                               float* __restrict__ out) {
  __shared__ float w1s[128 * 128];  // 64 KB, elem (j,c) at j*128 + (c ^ (j&31))
  __shared__ float rhs_[128];
  __shared__ float ros_[128];
  __shared__ float c0s[128];
  __shared__ float b1s[128];
  __shared__ float bpart[2][128];
  __shared__ float apl[2][128];

  const int t = threadIdx.x;
  const int p = blockIdx.x;
  const int jk = t & 127;
  const int half = t >> 7;

  // stage W1[:, 128p:128p+128)  (row stride 1024 floats = 256 float4)
  const float4* __restrict__ W14 = reinterpret_cast<const float4*>(W1);
#pragma unroll
  for (int itr = 0; itr < 16; ++itr) {
    const int e4 = itr * 256 + t;
    const int j = e4 >> 5;
    const int c4 = e4 & 31;
    const float4 w = W14[j * 256 + p * 32 + c4];
    const int rb = j * 128;
    const int sw = j & 31;
    const int c = c4 * 4;
    w1s[rb + ((c + 0) ^ sw)] = w.x;
    w1s[rb + ((c + 1) ^ sw)] = w.y;
    w1s[rb + ((c + 2) ^ sw)] = w.z;
    w1s[rb + ((c + 3) ^ sw)] = w.w;
  }
  // c0 column-sum of part[npart][128], fixed deterministic order (replicated)
  {
    float s = 0.f;
    const int hq = npart >> 1;
    const int q0 = half * hq;
#pragma unroll 8
    for (int q = 0; q < (npart >> 1); ++q) s += part[(q0 + q) * 128 + jk];
    bpart[half][jk] = s;
  }
  __syncthreads();
  if (half == 0) {
    c0s[jk] = bpart[0][jk] + bpart[1][jk];
    b1s[jk] = b1[jk];
  }
  const float b2v = (half == 0) ? b2[p * 128 + jk] : 0.f;
  const int niter = *niterp;
  float hreg = 0.f, mh = 0.f, vh = 0.f;
  float oreg = 0.f, mo = 0.f, vo = 0.f;
  __syncthreads();

  for (int it = 1; it <= niter; ++it) {
    // publish rho(h), rho(o) of the CURRENT carry
    if (half == 0) {
      rhs_[jk] = rho(hreg);
      ros_[jk] = rho(oreg);
    }
    __syncthreads();
    // b_k = sum_j rh_j W1[j,k]  (local cols); partial_a_j over local cols
    float accB = 0.f, accA = 0.f;
    const int x0 = half * 64;
#pragma unroll 8
    for (int u = 0; u < 64; ++u) {
      const int j = x0 + u;
      accB = fmaf(rhs_[j], w1s[j * 128 + (jk ^ (j & 31))], accB);
    }
#pragma unroll 8
    for (int u = 0; u < 64; ++u) {
      const int c = x0 + u;
      accA = fmaf(w1s[jk * 128 + (c ^ (jk & 31))], ros_[c], accA);
    }
    bpart[half][jk] = accB;
    apl[half][jk] = accA;
    __syncthreads();
    const int par = it & 1;
    float bsum = 0.f;
    if (half == 0) {
      bsum = bpart[0][jk] + bpart[1][jk];
      const float pa = apl[0][jk] + apl[1][jk];
      __hip_atomic_store(&aPartG[par * 1024 + p * 128 + jk], pa,
                         __ATOMIC_RELAXED, __HIP_MEMORY_SCOPE_AGENT);
    }
    __syncthreads();
    // device-scope phase barrier (monotone counter, reset by k1 each launch)
    if (t == 0) {
      __threadfence();
      __hip_atomic_fetch_add(cnt, 1, __ATOMIC_ACQ_REL, __HIP_MEMORY_SCOPE_AGENT);
      const int target = NBLK_B * it;
      while (__hip_atomic_load(cnt, __ATOMIC_ACQUIRE,
                               __HIP_MEMORY_SCOPE_AGENT) < target) {
        __builtin_amdgcn_s_sleep(2);
      }
    }
    __syncthreads();
    if (half == 0) {
      // a_j = (W1 @ rho(o))_j : fixed-order sum of the 8 partials
      float a = 0.f;
#pragma unroll
      for (int q = 0; q < NBLK_B; ++q)
        a += __hip_atomic_load(&aPartG[par * 1024 + q * 128 + jk],
                               __ATOMIC_RELAXED, __HIP_MEMORY_SCOPE_AGENT);
      const float tf = (float)it;
      const float bc1 = 1.0f - powf(0.9f, tf);
      const float bc2 = 1.0f - powf(0.999f, tf);
      {  // h update (replicated, bit-identical in every block)
        const float gh = drho(hreg) * (rhs_[jk] - b1s[jk] - c0s[jk] - a);
        mh = 0.9f * mh + 0.1f * gh;
        vh = 0.999f * vh + 0.001f * (gh * gh);
        const float mhat = mh / bc1;
        const float vhat = vh / bc2;
        hreg = hreg - 0.01f * mhat / (sqrtf(vhat) + 1e-8f);
      }
      {  // o update (owned segment)
        const float go = drho(oreg) * (ros_[jk] - b2v - bsum);
        mo = 0.9f * mo + 0.1f * go;
        vo = 0.999f * vo + 0.001f * (go * go);
        const float mhat = mo / bc1;
        const float vhat = vo / bc2;
        oreg = oreg - 0.01f * mhat / (sqrtf(vhat) + 1e-8f);
      }
    }
    // no extra sync: cross-thread LDS reads are fenced by the next
    // iteration's step-1/step-2 __syncthreads (see hazard analysis)
  }
  if (half == 0) out[p * 128 + jk] = oreg;
}

extern "C" void kernel_launch(void* const* d_in, const int* in_sizes, int n_in,
                              void* d_out, int out_size, void* d_ws,
                              size_t ws_size, hipStream_t stream) {
  const float* x  = (const float*)d_in[0];
  // d_in[1] = b0: constant in E w.r.t. (h,o) -> never needed
  const float* b1 = (const float*)d_in[2];
  const float* b2 = (const float*)d_in[3];
  const float* W0 = (const float*)d_in[4];
  const float* W1 = (const float*)d_in[5];
  const int*   ni = (const int*)d_in[6];
  float* out = (float*)d_out;

  char* ws = (char*)d_ws;
  int*   cnt    = (int*)ws;                   // [0,128): barrier counter
  float* aPartG = (float*)(ws + 128);         // 2 x 8 x 128 f32 = 8 KB
  float* part   = (float*)(ws + 128 + 8192);  // nblk x 128 f32

  const int nrows = in_sizes[0];   // 262144
  const int nblk = nrows >> 9;     // 512 rows per block -> 512 blocks

  hipLaunchKernelGGL(k1_xw0, dim3(nblk), dim3(256), 0, stream,
                     x, W0, part, cnt);
  hipLaunchKernelGGL(k2_iter, dim3(NBLK_B), dim3(256), 0, stream,
                     part, nblk, W1, b1, b2, ni, aPartG, cnt, out);
}

// Round 2
// 100.602 us; speedup vs baseline: 1.2361x; 1.2361x over previous
//
#include <hip/hip_runtime.h>
#include <math.h>

#define NBLK_B 8  // phase-B persistent blocks (cols of W1 partitioned 8 x 128)

__device__ __forceinline__ float rho(float s) {
  return fminf(fmaxf(s, 0.0f), 1.0f);
}

// d/ds clip(s,0,1) with JAX maximum/minimum tie-gradient = 0.5
__device__ __forceinline__ float drho(float s) {
  if (s < 0.0f || s > 1.0f) return 0.0f;
  float g = 1.0f;
  if (s == 0.0f) g *= 0.5f;
  if (s == 1.0f) g *= 0.5f;
  return g;
}

// ---------------- Phase A: per-block partials of c0 = rho(x) @ W0 ----------
// W0 row-major [N,128]; each block handles ROWS rows; partials -> ws (det.)
template <int ROWS>
__global__ __launch_bounds__(256) void k1_xw0(const float* __restrict__ x,
                                              const float* __restrict__ W0,
                                              float* __restrict__ part,
                                              int* __restrict__ flags) {
  __shared__ float xs[ROWS];
  __shared__ float red[8][132];  // +4 pad to spread store banks
  const int t = threadIdx.x;
  const int b = blockIdx.x;
  if (b == 0 && t < NBLK_B) flags[t * 32] = 0;  // reset phase-B flags
  const int r0 = b * ROWS;
  for (int i = t; i < ROWS; i += 256) xs[i] = rho(x[r0 + i]);
  __syncthreads();
  const int cq = t & 31;   // float4 column group (32 x 4 = 128 cols)
  const int rg = t >> 5;   // row group 0..7
  constexpr int GR = ROWS / 8;
  const float4* __restrict__ W4 = reinterpret_cast<const float4*>(W0);
  float ax = 0.f, ay = 0.f, az = 0.f, aw = 0.f;
  const int base = (r0 + rg * GR) * 32 + cq;
#pragma unroll 8
  for (int i = 0; i < GR; ++i) {
    const float xv = xs[rg * GR + i];
    const float4 w = W4[base + i * 32];
    ax = fmaf(xv, w.x, ax);
    ay = fmaf(xv, w.y, ay);
    az = fmaf(xv, w.z, az);
    aw = fmaf(xv, w.w, aw);
  }
  red[rg][cq * 4 + 0] = ax;
  red[rg][cq * 4 + 1] = ay;
  red[rg][cq * 4 + 2] = az;
  red[rg][cq * 4 + 3] = aw;
  __syncthreads();
  if (t < 128) {
    float s = 0.f;
#pragma unroll
    for (int g = 0; g < 8; ++g) s += red[g][t];
    part[b * 128 + t] = s;
  }
}

// ---------------- Phase B: persistent 8-block Adam iterator -----------------
// Block p owns W1 cols [128p,128p+128) in XOR-swizzled LDS, o-segment in regs;
// h (128) replicated bit-identically. Per iteration only the 128-float a-partial
// crosses blocks; sync is per-block flag slots (no RMW contention).
__global__ __launch_bounds__(256) void k2_iter(const float* __restrict__ part,
                                               const int npart,
                                               const float* __restrict__ W1,
                                               const float* __restrict__ b1,
                                               const float* __restrict__ b2,
                                               const int* __restrict__ niterp,
                                               float* __restrict__ c0part,
                                               float* __restrict__ aPartG,
                                               int* __restrict__ flags,
                                               float* __restrict__ out) {
  __shared__ float w1s[128 * 128];  // 64 KB, elem (j,c) at j*128 + (c ^ (j&31))
  __shared__ float rhs_[128];
  __shared__ float ros_[128];
  __shared__ float c0s[128];
  __shared__ float b1s[128];
  __shared__ float bpart[2][128];
  __shared__ float apl[2][128];

  const int t = threadIdx.x;
  const int p = blockIdx.x;
  const int jk = t & 127;
  const int half = t >> 7;

  // stage W1[:, 128p:128p+128)  (row stride 1024 floats = 256 float4)
  const float4* __restrict__ W14 = reinterpret_cast<const float4*>(W1);
#pragma unroll
  for (int itr = 0; itr < 16; ++itr) {
    const int e4 = itr * 256 + t;
    const int j = e4 >> 5;
    const int c4 = e4 & 31;
    const float4 w = W14[j * 256 + p * 32 + c4];
    const int rb = j * 128;
    const int sw = j & 31;
    const int c = c4 * 4;
    w1s[rb + ((c + 0) ^ sw)] = w.x;
    w1s[rb + ((c + 1) ^ sw)] = w.y;
    w1s[rb + ((c + 2) ^ sw)] = w.z;
    w1s[rb + ((c + 3) ^ sw)] = w.w;
  }
  // local c0 partial: sum rows [p*seg, (p+1)*seg) of part, fixed order
  {
    const int seg = npart >> 3;          // rows per block
    const int hseg = seg >> 1;
    float s = 0.f;
    const int rbase = p * seg + half * hseg;
#pragma unroll 8
    for (int q = 0; q < hseg; ++q) s += part[(rbase + q) * 128 + jk];
    bpart[half][jk] = s;
  }
  __syncthreads();
  if (half == 0)
    __hip_atomic_store(&c0part[p * 128 + jk], bpart[0][jk] + bpart[1][jk],
                       __ATOMIC_RELAXED, __HIP_MEMORY_SCOPE_AGENT);
  __syncthreads();
  if (t == 0) {
    __threadfence();
    __hip_atomic_store(&flags[p * 32], 1, __ATOMIC_RELEASE,
                       __HIP_MEMORY_SCOPE_AGENT);
  }
  // overlap: scalar loads while the c0 flag propagates
  if (half == 0) b1s[jk] = b1[jk];
  const float b2v = (half == 0) ? b2[p * 128 + jk] : 0.f;
  const int niter = *niterp;
  if (half == 0) { rhs_[jk] = 0.f; ros_[jk] = 0.f; }
  float hreg = 0.f, mh = 0.f, vh = 0.f;
  float oreg = 0.f, mo = 0.f, vo = 0.f;
  // c0 pre-exchange: wait for all 8 slices, reduce in fixed order (replicated)
  if (t < NBLK_B) {
    while (__hip_atomic_load(&flags[t * 32], __ATOMIC_ACQUIRE,
                             __HIP_MEMORY_SCOPE_AGENT) < 1)
      __builtin_amdgcn_s_sleep(1);
  }
  __syncthreads();
  if (half == 0) {
    float s = 0.f;
#pragma unroll
    for (int q = 0; q < NBLK_B; ++q)
      s += __hip_atomic_load(&c0part[q * 128 + jk], __ATOMIC_RELAXED,
                             __HIP_MEMORY_SCOPE_AGENT);
    c0s[jk] = s;
  }
  __syncthreads();

  for (int it = 1; it <= niter; ++it) {
    const int par = it & 1;
    const int x0 = half * 64;
    // 1) a-partial first (the only cross-block datum) -> publish ASAP
    float accA = 0.f;
#pragma unroll 8
    for (int u = 0; u < 64; ++u) {
      const int c = x0 + u;
      accA = fmaf(w1s[jk * 128 + (c ^ (jk & 31))], ros_[c], accA);
    }
    apl[half][jk] = accA;
    __syncthreads();  // S1
    if (half == 0)
      __hip_atomic_store(&aPartG[par * 1024 + p * 128 + jk],
                         apl[0][jk] + apl[1][jk], __ATOMIC_RELAXED,
                         __HIP_MEMORY_SCOPE_AGENT);
    __syncthreads();  // S2
    if (t == 0) {
      __threadfence();
      __hip_atomic_store(&flags[p * 32], it + 1, __ATOMIC_RELEASE,
                         __HIP_MEMORY_SCOPE_AGENT);
    }
    // 2) local work under the flag's propagation: b_k for owned cols
    float accB = 0.f;
#pragma unroll 8
    for (int u = 0; u < 64; ++u) {
      const int j = x0 + u;
      accB = fmaf(rhs_[j], w1s[j * 128 + (jk ^ (j & 31))], accB);
    }
    bpart[half][jk] = accB;
    __syncthreads();  // S3
    // 3) parallel poll: lane q watches block q's flag slot
    if (t < NBLK_B) {
      while (__hip_atomic_load(&flags[t * 32], __ATOMIC_ACQUIRE,
                               __HIP_MEMORY_SCOPE_AGENT) < it + 1)
        __builtin_amdgcn_s_sleep(1);
    }
    __syncthreads();  // S4
    if (half == 0) {
      const float bsum = bpart[0][jk] + bpart[1][jk];
      float a = 0.f;
#pragma unroll
      for (int q = 0; q < NBLK_B; ++q)
        a += __hip_atomic_load(&aPartG[par * 1024 + q * 128 + jk],
                               __ATOMIC_RELAXED, __HIP_MEMORY_SCOPE_AGENT);
      const float tf = (float)it;
      const float bc1 = 1.0f - powf(0.9f, tf);
      const float bc2 = 1.0f - powf(0.999f, tf);
      {  // h update (replicated, bit-identical in every block)
        const float gh = drho(hreg) * (rhs_[jk] - b1s[jk] - c0s[jk] - a);
        mh = 0.9f * mh + 0.1f * gh;
        vh = 0.999f * vh + 0.001f * (gh * gh);
        hreg = hreg - 0.01f * (mh / bc1) / (sqrtf(vh / bc2) + 1e-8f);
      }
      {  // o update (owned segment)
        const float go = drho(oreg) * (ros_[jk] - b2v - bsum);
        mo = 0.9f * mo + 0.1f * go;
        vo = 0.999f * vo + 0.001f * (go * go);
        oreg = oreg - 0.01f * (mo / bc1) / (sqrtf(vo / bc2) + 1e-8f);
      }
      rhs_[jk] = rho(hreg);
      ros_[jk] = rho(oreg);
    }
    __syncthreads();  // S5
  }
  if (half == 0) out[p * 128 + jk] = oreg;
}

extern "C" void kernel_launch(void* const* d_in, const int* in_sizes, int n_in,
                              void* d_out, int out_size, void* d_ws,
                              size_t ws_size, hipStream_t stream) {
  const float* x  = (const float*)d_in[0];
  // d_in[1] = b0: constant in E w.r.t. (h,o) -> never needed
  const float* b1 = (const float*)d_in[2];
  const float* b2 = (const float*)d_in[3];
  const float* W0 = (const float*)d_in[4];
  const float* W1 = (const float*)d_in[5];
  const int*   ni = (const int*)d_in[6];
  float* out = (float*)d_out;

  char* ws = (char*)d_ws;
  int*   flags  = (int*)ws;                    // 8 slots x 128 B = 1 KB
  float* c0part = (float*)(ws + 1024);         // 8 x 128 f32 = 4 KB
  float* aPartG = (float*)(ws + 1024 + 4096);  // 2 x 8 x 128 f32 = 8 KB
  float* part   = (float*)(ws + 13312);        // nblk x 128 f32

  const int nrows = in_sizes[0];  // 262144
  const size_t hdr = 13312;
  int nblk;
  if (ws_size >= hdr + (size_t)(nrows / 256) * 512) {
    nblk = nrows / 256;  // 1024 blocks, 4/CU
    hipLaunchKernelGGL(k1_xw0<256>, dim3(nblk), dim3(256), 0, stream,
                       x, W0, part, flags);
  } else if (ws_size >= hdr + (size_t)(nrows / 512) * 512) {
    nblk = nrows / 512;
    hipLaunchKernelGGL(k1_xw0<512>, dim3(nblk), dim3(256), 0, stream,
                       x, W0, part, flags);
  } else {
    nblk = nrows / 1024;
    hipLaunchKernelGGL(k1_xw0<1024>, dim3(nblk), dim3(256), 0, stream,
                       x, W0, part, flags);
  }
  hipLaunchKernelGGL(k2_iter, dim3(NBLK_B), dim3(256), 0, stream,
                     part, nblk, W1, b1, b2, ni, c0part, aPartG, flags, out);
}